// Round 2
// baseline (728.965 us; speedup 1.0000x reference)
//
#include <hip/hip_runtime.h>
#include <math.h>

#define UNITS 1024
#define EMBD  256
#define BATCH 64
#define TLEN  128
#define VOCAB 32000
#define GIN_D (UNITS + EMBD)   // 1280

typedef short short8 __attribute__((ext_vector_type(8)));
typedef float f32x4  __attribute__((ext_vector_type(4)));

__device__ __forceinline__ unsigned short f2bf(float f) {
    unsigned int u = __float_as_uint(f);
    u += 0x7fffu + ((u >> 16) & 1u);   // RNE
    return (unsigned short)(u >> 16);
}
__device__ __forceinline__ unsigned int packbf(float lo, float hi) {
    return (unsigned int)f2bf(lo) | ((unsigned int)f2bf(hi) << 16);
}

// ---------------- K1: c[b,j] += hidden[b,k0:k0+256] @ W2[k0:,j]  (K-split 4) --------
__global__ __launch_bounds__(256) void k_c(const float* __restrict__ hidden,
                                           const float* __restrict__ W2,
                                           const float* __restrict__ b1,
                                           const float* __restrict__ b2,
                                           float* __restrict__ c) {
    const int lane = threadIdx.x & 63;
    const int j = blockIdx.x * 64 + lane;
    const int b = blockIdx.y * 4 + (threadIdx.x >> 6);
    const int k0 = blockIdx.z * 256;
    const float* hrow = hidden + (size_t)b * UNITS + k0;
    const float* wcol = W2 + (size_t)k0 * UNITS + j;
    float acc = 0.f;
#pragma unroll 8
    for (int k = 0; k < 256; ++k)
        acc = fmaf(hrow[k], wcol[(size_t)k * UNITS], acc);
    if (blockIdx.z == 0) acc += b1[j] + b2[j];
    atomicAdd(&c[(size_t)b * UNITS + j], acc);
}

// ---------------- K2: score via bf16 MFMA (unchanged) -------------------------------
__global__ __launch_bounds__(256, 2) void k_score(const float* __restrict__ enc,
                                                  const float* __restrict__ W1,
                                                  const float* __restrict__ c,
                                                  const float* __restrict__ V,
                                                  float* __restrict__ score) {
    __shared__ unsigned short As[128 * 72];
    __shared__ unsigned short Bs[128 * 72];
    const int jt   = blockIdx.x;         // 0..7
    const int b    = blockIdx.y;         // 0..63
    const int tid  = threadIdx.x;
    const int lane = tid & 63;
    const int wid  = tid >> 6;           // 0..3
    const int wr   = wid & 1;
    const int wc   = wid >> 1;
    const int quad = lane >> 4;
    const int l16  = lane & 15;

    const float* encb = enc + (size_t)b * TLEN * UNITS;
    const float* w1b  = W1 + jt * 128;

    f32x4 acc[4][4];
#pragma unroll
    for (int i = 0; i < 4; ++i)
#pragma unroll
        for (int j = 0; j < 4; ++j)
            acc[i][j] = (f32x4){0.f, 0.f, 0.f, 0.f};

    const int ar = tid >> 4;
    const int ac = tid & 15;
    const int bp = tid >> 5;
    const int bj = tid & 31;

    for (int kc = 0; kc < UNITS; kc += 64) {
        float4 av[8];
#pragma unroll
        for (int rr = 0; rr < 8; ++rr)
            av[rr] = *(const float4*)(encb + (size_t)(ar + rr * 16) * UNITS + kc + ac * 4);
        float4 bv0[4], bv1[4];
#pragma unroll
        for (int kk = 0; kk < 4; ++kk) {
            const int k0 = 2 * (bp + 8 * kk);
            bv0[kk] = *(const float4*)(w1b + (size_t)(kc + k0) * UNITS + bj * 4);
            bv1[kk] = *(const float4*)(w1b + (size_t)(kc + k0 + 1) * UNITS + bj * 4);
        }
        __syncthreads();
#pragma unroll
        for (int rr = 0; rr < 8; ++rr) {
            ushort4 h;
            h.x = f2bf(av[rr].x); h.y = f2bf(av[rr].y);
            h.z = f2bf(av[rr].z); h.w = f2bf(av[rr].w);
            *(ushort4*)&As[(ar + rr * 16) * 72 + ac * 4] = h;
        }
#pragma unroll
        for (int kk = 0; kk < 4; ++kk) {
            const int k0 = 2 * (bp + 8 * kk);
            *(unsigned int*)&Bs[(bj * 4 + 0) * 72 + k0] = packbf(bv0[kk].x, bv1[kk].x);
            *(unsigned int*)&Bs[(bj * 4 + 1) * 72 + k0] = packbf(bv0[kk].y, bv1[kk].y);
            *(unsigned int*)&Bs[(bj * 4 + 2) * 72 + k0] = packbf(bv0[kk].z, bv1[kk].z);
            *(unsigned int*)&Bs[(bj * 4 + 3) * 72 + k0] = packbf(bv0[kk].w, bv1[kk].w);
        }
        __syncthreads();
#pragma unroll
        for (int kk = 0; kk < 2; ++kk) {
            const int kb = kk * 32 + quad * 8;
            short8 af[4], bfr[4];
#pragma unroll
            for (int mt = 0; mt < 4; ++mt)
                af[mt] = *(const short8*)&As[(wr * 64 + mt * 16 + l16) * 72 + kb];
#pragma unroll
            for (int nt = 0; nt < 4; ++nt)
                bfr[nt] = *(const short8*)&Bs[(wc * 64 + nt * 16 + l16) * 72 + kb];
#pragma unroll
            for (int mt = 0; mt < 4; ++mt)
#pragma unroll
                for (int nt = 0; nt < 4; ++nt)
                    acc[mt][nt] = __builtin_amdgcn_mfma_f32_16x16x32_bf16(
                        af[mt], bfr[nt], acc[mt][nt], 0, 0, 0);
        }
    }

    float cv[4], vv[4];
#pragma unroll
    for (int nt = 0; nt < 4; ++nt) {
        const int col = wc * 64 + nt * 16 + l16;
        cv[nt] = c[(size_t)b * UNITS + jt * 128 + col];
        vv[nt] = V[jt * 128 + col];
    }
    float rs[16];
#pragma unroll
    for (int mt = 0; mt < 4; ++mt)
#pragma unroll
        for (int reg = 0; reg < 4; ++reg) {
            float s = 0.f;
#pragma unroll
            for (int nt = 0; nt < 4; ++nt)
                s += tanhf(acc[mt][nt][reg] + cv[nt]) * vv[nt];
            rs[mt * 4 + reg] = s;
        }
#pragma unroll
    for (int off = 1; off < 16; off <<= 1)
#pragma unroll
        for (int i = 0; i < 16; ++i)
            rs[i] += __shfl_xor(rs[i], off);
    if (l16 == 0) {
#pragma unroll
        for (int mt = 0; mt < 4; ++mt)
#pragma unroll
            for (int reg = 0; reg < 4; ++reg)
                atomicAdd(&score[b * TLEN + wr * 64 + mt * 16 + quad * 4 + reg],
                          rs[mt * 4 + reg]);
    }
}

// ---------------- K3: softmax over t ------------------------------------------------
__global__ void k_softmax(const float* __restrict__ score, float* __restrict__ attw) {
    const int b = blockIdx.x;
    const int lane = threadIdx.x;
    float s0 = score[b * TLEN + lane];
    float s1 = score[b * TLEN + 64 + lane];
    float m = fmaxf(s0, s1);
#pragma unroll
    for (int off = 1; off < 64; off <<= 1) m = fmaxf(m, __shfl_xor(m, off));
    const float e0 = expf(s0 - m);
    const float e1 = expf(s1 - m);
    float s = e0 + e1;
#pragma unroll
    for (int off = 1; off < 64; off <<= 1) s += __shfl_xor(s, off);
    const float inv = 1.f / s;
    attw[b * TLEN + lane] = e0 * inv;
    attw[b * TLEN + 64 + lane] = e1 * inv;
}

// ---------------- K4: context -> gin[:, :1024] --------------------------------------
__global__ __launch_bounds__(256) void k_context(const float* __restrict__ enc,
                                                 const float* __restrict__ attw,
                                                 float* __restrict__ gin) {
    const int b = blockIdx.y;
    const int k = blockIdx.x * 256 + threadIdx.x;
    __shared__ float w[TLEN];
    if (threadIdx.x < TLEN) w[threadIdx.x] = attw[b * TLEN + threadIdx.x];
    __syncthreads();
    const float* e = enc + (size_t)b * TLEN * UNITS + k;
    float acc = 0.f;
#pragma unroll 8
    for (int t = 0; t < TLEN; ++t)
        acc = fmaf(w[t], e[(size_t)t * UNITS], acc);
    gin[(size_t)b * GIN_D + k] = acc;
}

// ---------------- K5: embedding gather -> gin[:, 1024:1280] -------------------------
__global__ void k_embed(const int* __restrict__ x, const float* __restrict__ emb,
                        float* __restrict__ gin) {
    const int b = blockIdx.x;
    const int e = threadIdx.x;
    const int row = x[b];
    gin[(size_t)b * GIN_D + UNITS + e] = emb[(size_t)row * EMBD + e];
}

// ---------------- K6a: GRU gate accumulation (K-split 5, atomics) -------------------
__global__ __launch_bounds__(256) void k_gru_acc(const float* __restrict__ gin,
                                                 const float* __restrict__ gru_k,
                                                 const float* __restrict__ gru_b,
                                                 float* __restrict__ gz,
                                                 float* __restrict__ gh) {
    const int lane = threadIdx.x & 63;
    const int i = blockIdx.x * 64 + lane;
    const int b = blockIdx.y * 4 + (threadIdx.x >> 6);
    const int k0 = blockIdx.z * 256;
    const float* g = gin + (size_t)b * GIN_D + k0;
    const float* wz = gru_k + (size_t)k0 * 3072 + i;
    const float* wh = wz + 2048;
    float az = 0.f, ah = 0.f;
#pragma unroll 8
    for (int k = 0; k < 256; ++k) {
        const float gv = g[k];
        az = fmaf(gv, wz[(size_t)k * 3072], az);
        ah = fmaf(gv, wh[(size_t)k * 3072], ah);
    }
    if (blockIdx.z == 0) { az += gru_b[i]; ah += gru_b[2048 + i]; }
    atomicAdd(&gz[(size_t)b * UNITS + i], az);
    atomicAdd(&gh[(size_t)b * UNITS + i], ah);
}

// ---------------- K6b: GRU finalize -------------------------------------------------
__global__ __launch_bounds__(256) void k_gru_fin(const float* __restrict__ gz,
                                                 const float* __restrict__ gh,
                                                 float* __restrict__ state,
                                                 float* __restrict__ stateT) {
    const int lane = threadIdx.x & 63;
    const int i = blockIdx.x * 64 + lane;
    const int b = blockIdx.y * 4 + (threadIdx.x >> 6);
    const float az = gz[(size_t)b * UNITS + i];
    const float ah = gh[(size_t)b * UNITS + i];
    const float z = 1.f / (1.f + expf(-az));
    const float hh = tanhf(ah);
    const float st = (1.f - z) * hh;
    state[(size_t)b * UNITS + i] = st;
    stateT[(size_t)i * BATCH + b] = st;
}

// ---------------- K7: logits = stateT @ fc_W + fc_b ---------------------------------
// No K-split, no atomics. 500 blocks x 256 threads; wave w: cols [bx*64,+64),
// batches [16w,+16). Latency fix vs R0: explicit register rings.
//   - weight ring w[16]: row k+u reloaded with row k+u+16  (lookahead 16 rows
//     ~ 540-1100 SIMD-cy at 2 waves/SIMD -> covers HBM/L3 latency)
//   - state ring s[8][4xfloat4]: row k+u (slot u&7) reloaded with row k+u+8
//     (lookahead 8 rows ~ 540 SIMD-cy -> covers L2/L3 latency)
// FMAs precede the slot reload in each sub-step so old values are consumed
// before the load overwrites the ring registers (no mov-renaming needed).
// All ring indices compile-time (full unroll) per rule #20.
#define FMA16V(W, S0, S1, S2, S3)                                             \
    {                                                                         \
        const float w_ = (W);                                                 \
        acc[0]  = fmaf((S0).x, w_, acc[0]);  acc[1]  = fmaf((S0).y, w_, acc[1]); \
        acc[2]  = fmaf((S0).z, w_, acc[2]);  acc[3]  = fmaf((S0).w, w_, acc[3]); \
        acc[4]  = fmaf((S1).x, w_, acc[4]);  acc[5]  = fmaf((S1).y, w_, acc[5]); \
        acc[6]  = fmaf((S1).z, w_, acc[6]);  acc[7]  = fmaf((S1).w, w_, acc[7]); \
        acc[8]  = fmaf((S2).x, w_, acc[8]);  acc[9]  = fmaf((S2).y, w_, acc[9]); \
        acc[10] = fmaf((S2).z, w_, acc[10]); acc[11] = fmaf((S2).w, w_, acc[11]);\
        acc[12] = fmaf((S3).x, w_, acc[12]); acc[13] = fmaf((S3).y, w_, acc[13]);\
        acc[14] = fmaf((S3).z, w_, acc[14]); acc[15] = fmaf((S3).w, w_, acc[15]);\
    }

__global__ __launch_bounds__(256) void k_fc(const float* __restrict__ stateT,
                                            const float* __restrict__ fc_W,
                                            const float* __restrict__ fc_b,
                                            float* __restrict__ logits) {
    const int lane = threadIdx.x & 63;
    const int col  = blockIdx.x * 64 + lane;
    const int b0   = (int)(threadIdx.x >> 6) * 16;
    const float* wp = fc_W + col;
    const float* sp = stateT + b0;

    float acc[16];
#pragma unroll
    for (int i = 0; i < 16; ++i) acc[i] = 0.f;

    float  w[16];       // weight ring, 16 rows deep
    float4 s[8][4];     // state ring, 8 rows x 16 floats

#pragma unroll
    for (int u = 0; u < 16; ++u) w[u] = wp[(size_t)u * VOCAB];
#pragma unroll
    for (int r = 0; r < 8; ++r) {
        const float* srow = sp + (size_t)r * BATCH;
        s[r][0] = *(const float4*)(srow);
        s[r][1] = *(const float4*)(srow + 4);
        s[r][2] = *(const float4*)(srow + 8);
        s[r][3] = *(const float4*)(srow + 12);
    }

    // main loop covers rows 0..1007; all reload indices stay in bounds:
    // max weight reload row = 992+15+16 = 1023; max state reload row = 992+15+8 = 1015.
    for (int k = 0; k < UNITS - 16; k += 16) {
#pragma unroll
        for (int u = 0; u < 16; ++u) {
            const int r = u & 7;
            FMA16V(w[u], s[r][0], s[r][1], s[r][2], s[r][3]);
            w[u] = wp[(size_t)(k + u + 16) * VOCAB];
            const float* srow = sp + (size_t)(k + u + 8) * BATCH;
            s[r][0] = *(const float4*)(srow);
            s[r][1] = *(const float4*)(srow + 4);
            s[r][2] = *(const float4*)(srow + 8);
            s[r][3] = *(const float4*)(srow + 12);
        }
    }
    // epilogue rows 1008..1023: w[0..15] hold rows 1008..1023; s slots 0..7 hold
    // rows 1008..1015. First 8 sub-steps reload slots with rows 1016..1023.
#pragma unroll
    for (int u = 0; u < 16; ++u) {
        const int r = u & 7;
        FMA16V(w[u], s[r][0], s[r][1], s[r][2], s[r][3]);
        if (u < 8) {
            const float* srow = sp + (size_t)(1016 + u) * BATCH;
            s[r][0] = *(const float4*)(srow);
            s[r][1] = *(const float4*)(srow + 4);
            s[r][2] = *(const float4*)(srow + 8);
            s[r][3] = *(const float4*)(srow + 12);
        }
    }

    const float fb = fc_b[col];
#pragma unroll
    for (int i = 0; i < 16; ++i)
        logits[(size_t)(b0 + i) * VOCAB + col] = acc[i] + fb;
}

extern "C" void kernel_launch(void* const* d_in, const int* in_sizes, int n_in,
                              void* d_out, int out_size, void* d_ws, size_t ws_size,
                              hipStream_t stream) {
    const int*   x      = (const int*)  d_in[0];
    const float* hidden = (const float*)d_in[1];
    const float* enc    = (const float*)d_in[2];
    const float* emb    = (const float*)d_in[3];
    const float* W1     = (const float*)d_in[4];
    const float* b1     = (const float*)d_in[5];
    const float* W2     = (const float*)d_in[6];
    const float* b2     = (const float*)d_in[7];
    const float* V      = (const float*)d_in[8];
    // d_in[9] = bV: softmax-invariant. d_in[11] = gru_rk: multiplies h0==0. Both unused.
    const float* gru_k  = (const float*)d_in[10];
    const float* gru_b  = (const float*)d_in[12];
    const float* fc_W   = (const float*)d_in[13];
    const float* fc_b   = (const float*)d_in[14];

    float* out       = (float*)d_out;
    float* logits    = out;                          // 64*32000
    float* state_out = out + (size_t)BATCH * VOCAB;  // 64*1024
    float* attw      = state_out + (size_t)BATCH * UNITS;  // 64*128

    float* c      = (float*)d_ws;        // 65536 f
    float* score  = c + 65536;           // 8192 f
    float* gin    = score + 8192;        // 81920 f
    float* stateT = gin + 81920;         // 65536 f
    float* gz     = stateT + 65536;      // 65536 f
    float* gh     = gz + 65536;          // 65536 f   (total ~1.41 MB)

    hipMemsetAsync(c, 0, (size_t)BATCH * UNITS * sizeof(float), stream);
    hipMemsetAsync(score, 0, (size_t)BATCH * TLEN * sizeof(float), stream);
    hipMemsetAsync(gz, 0, (size_t)2 * BATCH * UNITS * sizeof(float), stream);

    k_c      <<<dim3(16, 16, 4), 256, 0, stream>>>(hidden, W2, b1, b2, c);
    k_score  <<<dim3(8, 64),     256, 0, stream>>>(enc, W1, c, V, score);
    k_softmax<<<64, 64, 0, stream>>>(score, attw);
    k_context<<<dim3(4, 64),     256, 0, stream>>>(enc, attw, gin);
    k_embed  <<<64, 256, 0, stream>>>(x, emb, gin);
    k_gru_acc<<<dim3(16, 16, 5), 256, 0, stream>>>(gin, gru_k, gru_b, gz, gh);
    k_gru_fin<<<dim3(16, 16),    256, 0, stream>>>(gz, gh, state_out, stateT);
    k_fc     <<<dim3(500),       256, 0, stream>>>(stateT, fc_W, fc_b, logits);
}

// Round 3
// 452.975 us; speedup vs baseline: 1.6093x; 1.6093x over previous
//
#include <hip/hip_runtime.h>
#include <math.h>

#define UNITS 1024
#define EMBD  256
#define BATCH 64
#define TLEN  128
#define VOCAB 32000
#define GIN_D (UNITS + EMBD)   // 1280

typedef short short8 __attribute__((ext_vector_type(8)));
typedef float f32x4  __attribute__((ext_vector_type(4)));

__device__ __forceinline__ unsigned short f2bf(float f) {
    unsigned int u = __float_as_uint(f);
    u += 0x7fffu + ((u >> 16) & 1u);   // RNE
    return (unsigned short)(u >> 16);
}
__device__ __forceinline__ unsigned int packbf(float lo, float hi) {
    return (unsigned int)f2bf(lo) | ((unsigned int)f2bf(hi) << 16);
}

// ---------------- K1: c[b,j] += hidden[b,k0:k0+256] @ W2[k0:,j]  (K-split 4) --------
__global__ __launch_bounds__(256) void k_c(const float* __restrict__ hidden,
                                           const float* __restrict__ W2,
                                           const float* __restrict__ b1,
                                           const float* __restrict__ b2,
                                           float* __restrict__ c) {
    const int lane = threadIdx.x & 63;
    const int j = blockIdx.x * 64 + lane;
    const int b = blockIdx.y * 4 + (threadIdx.x >> 6);
    const int k0 = blockIdx.z * 256;
    const float* hrow = hidden + (size_t)b * UNITS + k0;
    const float* wcol = W2 + (size_t)k0 * UNITS + j;
    float acc = 0.f;
#pragma unroll 8
    for (int k = 0; k < 256; ++k)
        acc = fmaf(hrow[k], wcol[(size_t)k * UNITS], acc);
    if (blockIdx.z == 0) acc += b1[j] + b2[j];
    atomicAdd(&c[(size_t)b * UNITS + j], acc);
}

// ---------------- K2: score via bf16 MFMA (unchanged) -------------------------------
__global__ __launch_bounds__(256, 2) void k_score(const float* __restrict__ enc,
                                                  const float* __restrict__ W1,
                                                  const float* __restrict__ c,
                                                  const float* __restrict__ V,
                                                  float* __restrict__ score) {
    __shared__ unsigned short As[128 * 72];
    __shared__ unsigned short Bs[128 * 72];
    const int jt   = blockIdx.x;         // 0..7
    const int b    = blockIdx.y;         // 0..63
    const int tid  = threadIdx.x;
    const int lane = tid & 63;
    const int wid  = tid >> 6;           // 0..3
    const int wr   = wid & 1;
    const int wc   = wid >> 1;
    const int quad = lane >> 4;
    const int l16  = lane & 15;

    const float* encb = enc + (size_t)b * TLEN * UNITS;
    const float* w1b  = W1 + jt * 128;

    f32x4 acc[4][4];
#pragma unroll
    for (int i = 0; i < 4; ++i)
#pragma unroll
        for (int j = 0; j < 4; ++j)
            acc[i][j] = (f32x4){0.f, 0.f, 0.f, 0.f};

    const int ar = tid >> 4;
    const int ac = tid & 15;
    const int bp = tid >> 5;
    const int bj = tid & 31;

    for (int kc = 0; kc < UNITS; kc += 64) {
        float4 av[8];
#pragma unroll
        for (int rr = 0; rr < 8; ++rr)
            av[rr] = *(const float4*)(encb + (size_t)(ar + rr * 16) * UNITS + kc + ac * 4);
        float4 bv0[4], bv1[4];
#pragma unroll
        for (int kk = 0; kk < 4; ++kk) {
            const int k0 = 2 * (bp + 8 * kk);
            bv0[kk] = *(const float4*)(w1b + (size_t)(kc + k0) * UNITS + bj * 4);
            bv1[kk] = *(const float4*)(w1b + (size_t)(kc + k0 + 1) * UNITS + bj * 4);
        }
        __syncthreads();
#pragma unroll
        for (int rr = 0; rr < 8; ++rr) {
            ushort4 h;
            h.x = f2bf(av[rr].x); h.y = f2bf(av[rr].y);
            h.z = f2bf(av[rr].z); h.w = f2bf(av[rr].w);
            *(ushort4*)&As[(ar + rr * 16) * 72 + ac * 4] = h;
        }
#pragma unroll
        for (int kk = 0; kk < 4; ++kk) {
            const int k0 = 2 * (bp + 8 * kk);
            *(unsigned int*)&Bs[(bj * 4 + 0) * 72 + k0] = packbf(bv0[kk].x, bv1[kk].x);
            *(unsigned int*)&Bs[(bj * 4 + 1) * 72 + k0] = packbf(bv0[kk].y, bv1[kk].y);
            *(unsigned int*)&Bs[(bj * 4 + 2) * 72 + k0] = packbf(bv0[kk].z, bv1[kk].z);
            *(unsigned int*)&Bs[(bj * 4 + 3) * 72 + k0] = packbf(bv0[kk].w, bv1[kk].w);
        }
        __syncthreads();
#pragma unroll
        for (int kk = 0; kk < 2; ++kk) {
            const int kb = kk * 32 + quad * 8;
            short8 af[4], bfr[4];
#pragma unroll
            for (int mt = 0; mt < 4; ++mt)
                af[mt] = *(const short8*)&As[(wr * 64 + mt * 16 + l16) * 72 + kb];
#pragma unroll
            for (int nt = 0; nt < 4; ++nt)
                bfr[nt] = *(const short8*)&Bs[(wc * 64 + nt * 16 + l16) * 72 + kb];
#pragma unroll
            for (int mt = 0; mt < 4; ++mt)
#pragma unroll
                for (int nt = 0; nt < 4; ++nt)
                    acc[mt][nt] = __builtin_amdgcn_mfma_f32_16x16x32_bf16(
                        af[mt], bfr[nt], acc[mt][nt], 0, 0, 0);
        }
    }

    float cv[4], vv[4];
#pragma unroll
    for (int nt = 0; nt < 4; ++nt) {
        const int col = wc * 64 + nt * 16 + l16;
        cv[nt] = c[(size_t)b * UNITS + jt * 128 + col];
        vv[nt] = V[jt * 128 + col];
    }
    float rs[16];
#pragma unroll
    for (int mt = 0; mt < 4; ++mt)
#pragma unroll
        for (int reg = 0; reg < 4; ++reg) {
            float s = 0.f;
#pragma unroll
            for (int nt = 0; nt < 4; ++nt)
                s += tanhf(acc[mt][nt][reg] + cv[nt]) * vv[nt];
            rs[mt * 4 + reg] = s;
        }
#pragma unroll
    for (int off = 1; off < 16; off <<= 1)
#pragma unroll
        for (int i = 0; i < 16; ++i)
            rs[i] += __shfl_xor(rs[i], off);
    if (l16 == 0) {
#pragma unroll
        for (int mt = 0; mt < 4; ++mt)
#pragma unroll
            for (int reg = 0; reg < 4; ++reg)
                atomicAdd(&score[b * TLEN + wr * 64 + mt * 16 + quad * 4 + reg],
                          rs[mt * 4 + reg]);
    }
}

// ---------------- K3: softmax over t ------------------------------------------------
__global__ void k_softmax(const float* __restrict__ score, float* __restrict__ attw) {
    const int b = blockIdx.x;
    const int lane = threadIdx.x;
    float s0 = score[b * TLEN + lane];
    float s1 = score[b * TLEN + 64 + lane];
    float m = fmaxf(s0, s1);
#pragma unroll
    for (int off = 1; off < 64; off <<= 1) m = fmaxf(m, __shfl_xor(m, off));
    const float e0 = expf(s0 - m);
    const float e1 = expf(s1 - m);
    float s = e0 + e1;
#pragma unroll
    for (int off = 1; off < 64; off <<= 1) s += __shfl_xor(s, off);
    const float inv = 1.f / s;
    attw[b * TLEN + lane] = e0 * inv;
    attw[b * TLEN + 64 + lane] = e1 * inv;
}

// ---------------- K4: context -> gin[:, :1024] --------------------------------------
__global__ __launch_bounds__(256) void k_context(const float* __restrict__ enc,
                                                 const float* __restrict__ attw,
                                                 float* __restrict__ gin) {
    const int b = blockIdx.y;
    const int k = blockIdx.x * 256 + threadIdx.x;
    __shared__ float w[TLEN];
    if (threadIdx.x < TLEN) w[threadIdx.x] = attw[b * TLEN + threadIdx.x];
    __syncthreads();
    const float* e = enc + (size_t)b * TLEN * UNITS + k;
    float acc = 0.f;
#pragma unroll 8
    for (int t = 0; t < TLEN; ++t)
        acc = fmaf(w[t], e[(size_t)t * UNITS], acc);
    gin[(size_t)b * GIN_D + k] = acc;
}

// ---------------- K5: embedding gather -> gin[:, 1024:1280] -------------------------
__global__ void k_embed(const int* __restrict__ x, const float* __restrict__ emb,
                        float* __restrict__ gin) {
    const int b = blockIdx.x;
    const int e = threadIdx.x;
    const int row = x[b];
    gin[(size_t)b * GIN_D + UNITS + e] = emb[(size_t)row * EMBD + e];
}

// ---------------- K6a: GRU gate accumulation (K-split 5, atomics) -------------------
__global__ __launch_bounds__(256) void k_gru_acc(const float* __restrict__ gin,
                                                 const float* __restrict__ gru_k,
                                                 const float* __restrict__ gru_b,
                                                 float* __restrict__ gz,
                                                 float* __restrict__ gh) {
    const int lane = threadIdx.x & 63;
    const int i = blockIdx.x * 64 + lane;
    const int b = blockIdx.y * 4 + (threadIdx.x >> 6);
    const int k0 = blockIdx.z * 256;
    const float* g = gin + (size_t)b * GIN_D + k0;
    const float* wz = gru_k + (size_t)k0 * 3072 + i;
    const float* wh = wz + 2048;
    float az = 0.f, ah = 0.f;
#pragma unroll 8
    for (int k = 0; k < 256; ++k) {
        const float gv = g[k];
        az = fmaf(gv, wz[(size_t)k * 3072], az);
        ah = fmaf(gv, wh[(size_t)k * 3072], ah);
    }
    if (blockIdx.z == 0) { az += gru_b[i]; ah += gru_b[2048 + i]; }
    atomicAdd(&gz[(size_t)b * UNITS + i], az);
    atomicAdd(&gh[(size_t)b * UNITS + i], ah);
}

// ---------------- K6b: GRU finalize -------------------------------------------------
__global__ __launch_bounds__(256) void k_gru_fin(const float* __restrict__ gz,
                                                 const float* __restrict__ gh,
                                                 float* __restrict__ state,
                                                 float* __restrict__ stateT) {
    const int lane = threadIdx.x & 63;
    const int i = blockIdx.x * 64 + lane;
    const int b = blockIdx.y * 4 + (threadIdx.x >> 6);
    const float az = gz[(size_t)b * UNITS + i];
    const float ah = gh[(size_t)b * UNITS + i];
    const float z = 1.f / (1.f + expf(-az));
    const float hh = tanhf(ah);
    const float st = (1.f - z) * hh;
    state[(size_t)b * UNITS + i] = st;
    stateT[(size_t)i * BATCH + b] = st;
}

// ---------------- K7: logits = stateT @ fc_W + fc_b ---------------------------------
// Block = 256 thr = 4 waves; tile = 256 cols x 16 batches; grid 125 x 4.
// State slice (1024x16, 64 KB) staged in LDS once -> state reads are broadcast
// ds_read_b128 (2-deep ring). Weight stream is the ONLY VMEM chain: 1 float4
// per row per lane, 4-deep ring => max 4 outstanding (vmcnt(3) expressible --
// the R1 failure was 80 outstanding > vmcnt's 6-bit max).
// K=1024 split over the 4 waves (256 rows each); cross-wave reduce in LDS
// (reusing the state buffer), no atomics. Per row: 1 VMEM + 4 DS + 64 FMA.
__global__ __launch_bounds__(256, 2) void k_fc(const float* __restrict__ stateT,
                                               const float* __restrict__ fc_W,
                                               const float* __restrict__ fc_b,
                                               float* __restrict__ logits) {
    __shared__ float sState[1024 * 16];   // 64 KB; reused as 16 KB reduce buffer
    const int tid  = threadIdx.x;
    const int lane = tid & 63;
    const int wid  = tid >> 6;            // 0..3 -> K quarter
    const int g0   = blockIdx.y * 16;     // batch group
    const int col0 = blockIdx.x * 256 + lane * 4;

    // stage stateT[:, g0:g0+16] -> sState[row][16]
#pragma unroll
    for (int it = 0; it < 16; ++it) {
        const int idx = tid + it * 256;   // 0..4095
        const int r = idx >> 2, cch = idx & 3;
        const float4 v = *(const float4*)(stateT + (size_t)r * BATCH + g0 + cch * 4);
        *(float4*)&sState[r * 16 + cch * 4] = v;
    }

    const int krow0 = wid * 256;
    const float* wbase = fc_W + col0;

    // weight ring depth 4 (issued before the barrier to overlap staging)
    float4 wr[4];
#pragma unroll
    for (int j = 0; j < 4; ++j)
        wr[j] = *(const float4*)(wbase + (size_t)(krow0 + j) * VOCAB);

    __syncthreads();

    float4 acc[16];
#pragma unroll
    for (int b = 0; b < 16; ++b) acc[b] = (float4){0.f, 0.f, 0.f, 0.f};

    // state ring depth 2 (16 floats per slot)
    float4 srng[2][4];
#pragma unroll
    for (int c = 0; c < 4; ++c)
        srng[0][c] = *(const float4*)&sState[krow0 * 16 + c * 4];

#define FC_SUBSTEP(J, PREFETCH_W, PREFETCH_S)                                  \
    {                                                                          \
        const int r = krow0 + k + (J);                                         \
        if (PREFETCH_S) {                                                      \
            _Pragma("unroll")                                                  \
            for (int c = 0; c < 4; ++c)                                        \
                srng[((J) + 1) & 1][c] = *(const float4*)&sState[(r + 1) * 16 + c * 4]; \
        }                                                                      \
        const float4 wv = wr[(J)];                                             \
        if (PREFETCH_W)                                                        \
            wr[(J)] = *(const float4*)(wbase + (size_t)(r + 4) * VOCAB);       \
        _Pragma("unroll")                                                      \
        for (int c = 0; c < 4; ++c) {                                          \
            const float4 sv = srng[(J) & 1][c];                                \
            acc[c * 4 + 0].x = fmaf(wv.x, sv.x, acc[c * 4 + 0].x);             \
            acc[c * 4 + 0].y = fmaf(wv.y, sv.x, acc[c * 4 + 0].y);             \
            acc[c * 4 + 0].z = fmaf(wv.z, sv.x, acc[c * 4 + 0].z);             \
            acc[c * 4 + 0].w = fmaf(wv.w, sv.x, acc[c * 4 + 0].w);             \
            acc[c * 4 + 1].x = fmaf(wv.x, sv.y, acc[c * 4 + 1].x);             \
            acc[c * 4 + 1].y = fmaf(wv.y, sv.y, acc[c * 4 + 1].y);             \
            acc[c * 4 + 1].z = fmaf(wv.z, sv.y, acc[c * 4 + 1].z);             \
            acc[c * 4 + 1].w = fmaf(wv.w, sv.y, acc[c * 4 + 1].w);             \
            acc[c * 4 + 2].x = fmaf(wv.x, sv.z, acc[c * 4 + 2].x);             \
            acc[c * 4 + 2].y = fmaf(wv.y, sv.z, acc[c * 4 + 2].y);             \
            acc[c * 4 + 2].z = fmaf(wv.z, sv.z, acc[c * 4 + 2].z);             \
            acc[c * 4 + 2].w = fmaf(wv.w, sv.z, acc[c * 4 + 2].w);             \
            acc[c * 4 + 3].x = fmaf(wv.x, sv.w, acc[c * 4 + 3].x);             \
            acc[c * 4 + 3].y = fmaf(wv.y, sv.w, acc[c * 4 + 3].y);             \
            acc[c * 4 + 3].z = fmaf(wv.z, sv.w, acc[c * 4 + 3].z);             \
            acc[c * 4 + 3].w = fmaf(wv.w, sv.w, acc[c * 4 + 3].w);             \
        }                                                                      \
    }

    // main loop: rows krow0 .. krow0+251 (prefetch always in-bounds)
    for (int k = 0; k < 252; k += 4) {
        FC_SUBSTEP(0, true, true)
        FC_SUBSTEP(1, true, true)
        FC_SUBSTEP(2, true, true)
        FC_SUBSTEP(3, true, true)
    }
    // epilogue: rows krow0+252 .. krow0+255
    {
        const int k = 252;
        FC_SUBSTEP(0, false, true)
        FC_SUBSTEP(1, false, true)
        FC_SUBSTEP(2, false, true)
        FC_SUBSTEP(3, false, false)
    }
#undef FC_SUBSTEP

    // cross-wave reduce in LDS (reuse sState[0..4095] = 16 KB)
    __syncthreads();
    float* rbuf = sState;
#pragma unroll 1
    for (int ph = 0; ph < 4; ++ph) {
        if (wid == ph) {
#pragma unroll
            for (int b = 0; b < 16; ++b) {
                float4* p = (float4*)&rbuf[b * 256 + lane * 4];
                if (ph == 0) {
                    *p = acc[b];
                } else {
                    float4 t = *p;
                    t.x += acc[b].x; t.y += acc[b].y;
                    t.z += acc[b].z; t.w += acc[b].w;
                    *p = t;
                }
            }
        }
        __syncthreads();
    }

    // write out: thread t -> batch (t>>4), cols (t&15)*16 .. +15
    const int bb = tid >> 4;
    const int ch = tid & 15;
    const int cbase = blockIdx.x * 256 + ch * 16;
    float* lp = logits + (size_t)(g0 + bb) * VOCAB + cbase;
#pragma unroll
    for (int q = 0; q < 4; ++q) {
        float4 t = *(float4*)&rbuf[bb * 256 + ch * 16 + q * 4];
        const float4 fb = *(const float4*)(fc_b + cbase + q * 4);
        t.x += fb.x; t.y += fb.y; t.z += fb.z; t.w += fb.w;
        *(float4*)(lp + q * 4) = t;
    }
}

extern "C" void kernel_launch(void* const* d_in, const int* in_sizes, int n_in,
                              void* d_out, int out_size, void* d_ws, size_t ws_size,
                              hipStream_t stream) {
    const int*   x      = (const int*)  d_in[0];
    const float* hidden = (const float*)d_in[1];
    const float* enc    = (const float*)d_in[2];
    const float* emb    = (const float*)d_in[3];
    const float* W1     = (const float*)d_in[4];
    const float* b1     = (const float*)d_in[5];
    const float* W2     = (const float*)d_in[6];
    const float* b2     = (const float*)d_in[7];
    const float* V      = (const float*)d_in[8];
    // d_in[9] = bV: softmax-invariant. d_in[11] = gru_rk: multiplies h0==0. Both unused.
    const float* gru_k  = (const float*)d_in[10];
    const float* gru_b  = (const float*)d_in[12];
    const float* fc_W   = (const float*)d_in[13];
    const float* fc_b   = (const float*)d_in[14];

    float* out       = (float*)d_out;
    float* logits    = out;                          // 64*32000
    float* state_out = out + (size_t)BATCH * VOCAB;  // 64*1024
    float* attw      = state_out + (size_t)BATCH * UNITS;  // 64*128

    float* c      = (float*)d_ws;        // 65536 f
    float* score  = c + 65536;           // 8192 f
    float* gin    = score + 8192;        // 81920 f
    float* stateT = gin + 81920;         // 65536 f
    float* gz     = stateT + 65536;      // 65536 f
    float* gh     = gz + 65536;          // 65536 f   (total ~1.41 MB)

    hipMemsetAsync(c, 0, (size_t)BATCH * UNITS * sizeof(float), stream);
    hipMemsetAsync(score, 0, (size_t)BATCH * TLEN * sizeof(float), stream);
    hipMemsetAsync(gz, 0, (size_t)2 * BATCH * UNITS * sizeof(float), stream);

    k_c      <<<dim3(16, 16, 4), 256, 0, stream>>>(hidden, W2, b1, b2, c);
    k_score  <<<dim3(8, 64),     256, 0, stream>>>(enc, W1, c, V, score);
    k_softmax<<<64, 64, 0, stream>>>(score, attw);
    k_context<<<dim3(4, 64),     256, 0, stream>>>(enc, attw, gin);
    k_embed  <<<64, 256, 0, stream>>>(x, emb, gin);
    k_gru_acc<<<dim3(16, 16, 5), 256, 0, stream>>>(gin, gru_k, gru_b, gz, gh);
    k_gru_fin<<<dim3(16, 16),    256, 0, stream>>>(gz, gh, state_out, stateT);
    k_fc     <<<dim3(125, 4),    256, 0, stream>>>(stateT, fc_W, fc_b, logits);
}

// Round 4
// 408.850 us; speedup vs baseline: 1.7830x; 1.1079x over previous
//
#include <hip/hip_runtime.h>
#include <math.h>

#define UNITS 1024
#define EMBD  256
#define BATCH 64
#define TLEN  128
#define VOCAB 32000
#define GIN_D (UNITS + EMBD)   // 1280

typedef short short8 __attribute__((ext_vector_type(8)));
typedef float f32x4  __attribute__((ext_vector_type(4)));

__device__ __forceinline__ unsigned short f2bf(float f) {
    unsigned int u = __float_as_uint(f);
    u += 0x7fffu + ((u >> 16) & 1u);   // RNE
    return (unsigned short)(u >> 16);
}

// ---------------- K0: W1T bf16 pre-transpose: w1t[j][k] = bf16(W1[k][j]) ------------
__global__ __launch_bounds__(256) void k_w1t(const float* __restrict__ W1,
                                             unsigned short* __restrict__ w1t) {
    __shared__ float t[64][65];
    const int tid = threadIdx.x;
    const int bx = blockIdx.x * 64;   // k base
    const int by = blockIdx.y * 64;   // j base
#pragma unroll
    for (int p = 0; p < 16; ++p) {
        const int idx = tid + p * 256;
        const int r = idx >> 6, cc = idx & 63;      // r: k-offset, cc: j-offset
        t[r][cc] = W1[(size_t)(bx + r) * UNITS + by + cc];
    }
    __syncthreads();
#pragma unroll
    for (int p = 0; p < 16; ++p) {
        const int idx = tid + p * 256;
        const int jr = idx >> 6, kc = idx & 63;     // jr: j-offset, kc: k-offset
        w1t[(size_t)(by + jr) * UNITS + bx + kc] = f2bf(t[kc][jr]);
    }
}

// ---------------- K1: c[b,j] += hidden[b,k0:k0+256] @ W2[k0:,j]  (K-split 4) --------
__global__ __launch_bounds__(256) void k_c(const float* __restrict__ hidden,
                                           const float* __restrict__ W2,
                                           const float* __restrict__ b1,
                                           const float* __restrict__ b2,
                                           float* __restrict__ c) {
    const int lane = threadIdx.x & 63;
    const int j = blockIdx.x * 64 + lane;
    const int b = blockIdx.y * 4 + (threadIdx.x >> 6);
    const int k0 = blockIdx.z * 256;
    const float* hrow = hidden + (size_t)b * UNITS + k0;
    const float* wcol = W2 + (size_t)k0 * UNITS + j;
    float acc = 0.f;
#pragma unroll 8
    for (int k = 0; k < 256; ++k)
        acc = fmaf(hrow[k], wcol[(size_t)k * UNITS], acc);
    if (blockIdx.z == 0) acc += b1[j] + b2[j];
    atomicAdd(&c[(size_t)b * UNITS + j], acc);
}

// ---------------- K2: score via bf16 MFMA, M=64 tile, bf16 W1T input ----------------
// Grid (128, 8): x = b*2 + half (M-tile), y = jt. flat = jt*128 + b*2+half; flat%8
// depends only on b*2+half -> all 16 blocks sharing enc[b] land on <=2 XCDs (L2 reuse).
// 4 blocks/CU (LDS 27.6 KB). Bs staged by linear short8 copies from pre-transposed
// bf16 W1T (R2's 16-way-conflict scatter eliminated). As staged f32->bf16 (64 rows).
__global__ __launch_bounds__(256, 4) void k_score(const float* __restrict__ enc,
                                                  const unsigned short* __restrict__ w1t,
                                                  const float* __restrict__ c,
                                                  const float* __restrict__ V,
                                                  float* __restrict__ score) {
    __shared__ unsigned short As[64 * 72];
    __shared__ unsigned short Bs[128 * 72];
    const int half = blockIdx.x & 1;     // M-half of the 128 t-rows
    const int b    = blockIdx.x >> 1;    // 0..63
    const int jt   = blockIdx.y;         // 0..7
    const int tid  = threadIdx.x;
    const int lane = tid & 63;
    const int wc   = tid >> 6;           // wave -> N quarter (32 cols)
    const int quad = lane >> 4;
    const int l16  = lane & 15;

    const float* encb = enc + (size_t)b * TLEN * UNITS + (size_t)half * 64 * UNITS;
    const unsigned short* w1b = w1t + (size_t)jt * 128 * UNITS;

    f32x4 acc[4][2];
#pragma unroll
    for (int i = 0; i < 4; ++i)
#pragma unroll
        for (int j = 0; j < 2; ++j)
            acc[i][j] = (f32x4){0.f, 0.f, 0.f, 0.f};

    const int ar = tid >> 4;   // 0..15 (A row group)
    const int ac = tid & 15;   // 0..15 (A col chunk: 4 floats)

    for (int kc = 0; kc < UNITS; kc += 64) {
        float4 av[4];
#pragma unroll
        for (int rr = 0; rr < 4; ++rr)
            av[rr] = *(const float4*)(encb + (size_t)(ar + rr * 16) * UNITS + kc + ac * 4);
        short8 bv[4];
#pragma unroll
        for (int p = 0; p < 4; ++p) {
            const int cidx = tid + p * 256;          // 0..1023
            const int row = cidx >> 3, ch = cidx & 7;
            bv[p] = *(const short8*)(w1b + (size_t)row * UNITS + kc + ch * 8);
        }
        __syncthreads();
#pragma unroll
        for (int rr = 0; rr < 4; ++rr) {
            ushort4 h;
            h.x = f2bf(av[rr].x); h.y = f2bf(av[rr].y);
            h.z = f2bf(av[rr].z); h.w = f2bf(av[rr].w);
            *(ushort4*)&As[(ar + rr * 16) * 72 + ac * 4] = h;
        }
#pragma unroll
        for (int p = 0; p < 4; ++p) {
            const int cidx = tid + p * 256;
            const int row = cidx >> 3, ch = cidx & 7;
            *(short8*)&Bs[row * 72 + ch * 8] = bv[p];
        }
        __syncthreads();
#pragma unroll
        for (int kk = 0; kk < 2; ++kk) {
            const int kb = kk * 32 + quad * 8;
            short8 af[4], bfr[2];
#pragma unroll
            for (int mt = 0; mt < 4; ++mt)
                af[mt] = *(const short8*)&As[(mt * 16 + l16) * 72 + kb];
#pragma unroll
            for (int nt = 0; nt < 2; ++nt)
                bfr[nt] = *(const short8*)&Bs[(wc * 32 + nt * 16 + l16) * 72 + kb];
#pragma unroll
            for (int mt = 0; mt < 4; ++mt)
#pragma unroll
                for (int nt = 0; nt < 2; ++nt)
                    acc[mt][nt] = __builtin_amdgcn_mfma_f32_16x16x32_bf16(
                        af[mt], bfr[nt], acc[mt][nt], 0, 0, 0);
        }
    }

    float cv[2], vv[2];
#pragma unroll
    for (int nt = 0; nt < 2; ++nt) {
        const int col = jt * 128 + wc * 32 + nt * 16 + l16;
        cv[nt] = c[(size_t)b * UNITS + col];
        vv[nt] = V[col];
    }
    float rs[16];
#pragma unroll
    for (int mt = 0; mt < 4; ++mt)
#pragma unroll
        for (int reg = 0; reg < 4; ++reg) {
            float s = 0.f;
#pragma unroll
            for (int nt = 0; nt < 2; ++nt)
                s += tanhf(acc[mt][nt][reg] + cv[nt]) * vv[nt];
            rs[mt * 4 + reg] = s;
        }
#pragma unroll
    for (int off = 1; off < 16; off <<= 1)
#pragma unroll
        for (int i = 0; i < 16; ++i)
            rs[i] += __shfl_xor(rs[i], off);
    if (l16 == 0) {
#pragma unroll
        for (int mt = 0; mt < 4; ++mt)
#pragma unroll
            for (int reg = 0; reg < 4; ++reg)
                atomicAdd(&score[b * TLEN + half * 64 + mt * 16 + quad * 4 + reg],
                          rs[mt * 4 + reg]);
    }
}

// ---------------- K3: softmax over t ------------------------------------------------
__global__ void k_softmax(const float* __restrict__ score, float* __restrict__ attw) {
    const int b = blockIdx.x;
    const int lane = threadIdx.x;
    float s0 = score[b * TLEN + lane];
    float s1 = score[b * TLEN + 64 + lane];
    float m = fmaxf(s0, s1);
#pragma unroll
    for (int off = 1; off < 64; off <<= 1) m = fmaxf(m, __shfl_xor(m, off));
    const float e0 = expf(s0 - m);
    const float e1 = expf(s1 - m);
    float s = e0 + e1;
#pragma unroll
    for (int off = 1; off < 64; off <<= 1) s += __shfl_xor(s, off);
    const float inv = 1.f / s;
    attw[b * TLEN + lane] = e0 * inv;
    attw[b * TLEN + 64 + lane] = e1 * inv;
}

// ---------------- K4: context -> gin[:, :1024] --------------------------------------
__global__ __launch_bounds__(256) void k_context(const float* __restrict__ enc,
                                                 const float* __restrict__ attw,
                                                 float* __restrict__ gin) {
    const int b = blockIdx.y;
    const int k = blockIdx.x * 256 + threadIdx.x;
    __shared__ float w[TLEN];
    if (threadIdx.x < TLEN) w[threadIdx.x] = attw[b * TLEN + threadIdx.x];
    __syncthreads();
    const float* e = enc + (size_t)b * TLEN * UNITS + k;
    float acc = 0.f;
#pragma unroll 8
    for (int t = 0; t < TLEN; ++t)
        acc = fmaf(w[t], e[(size_t)t * UNITS], acc);
    gin[(size_t)b * GIN_D + k] = acc;
}

// ---------------- K5: embedding gather -> gin[:, 1024:1280] -------------------------
__global__ void k_embed(const int* __restrict__ x, const float* __restrict__ emb,
                        float* __restrict__ gin) {
    const int b = blockIdx.x;
    const int e = threadIdx.x;
    const int row = x[b];
    gin[(size_t)b * GIN_D + UNITS + e] = emb[(size_t)row * EMBD + e];
}

// ---------------- K6a: GRU gate accumulation (K-split 5, atomics) -------------------
__global__ __launch_bounds__(256) void k_gru_acc(const float* __restrict__ gin,
                                                 const float* __restrict__ gru_k,
                                                 const float* __restrict__ gru_b,
                                                 float* __restrict__ gz,
                                                 float* __restrict__ gh) {
    const int lane = threadIdx.x & 63;
    const int i = blockIdx.x * 64 + lane;
    const int b = blockIdx.y * 4 + (threadIdx.x >> 6);
    const int k0 = blockIdx.z * 256;
    const float* g = gin + (size_t)b * GIN_D + k0;
    const float* wz = gru_k + (size_t)k0 * 3072 + i;
    const float* wh = wz + 2048;
    float az = 0.f, ah = 0.f;
#pragma unroll 8
    for (int k = 0; k < 256; ++k) {
        const float gv = g[k];
        az = fmaf(gv, wz[(size_t)k * 3072], az);
        ah = fmaf(gv, wh[(size_t)k * 3072], ah);
    }
    if (blockIdx.z == 0) { az += gru_b[i]; ah += gru_b[2048 + i]; }
    atomicAdd(&gz[(size_t)b * UNITS + i], az);
    atomicAdd(&gh[(size_t)b * UNITS + i], ah);
}

// ---------------- K6b: GRU finalize -------------------------------------------------
__global__ __launch_bounds__(256) void k_gru_fin(const float* __restrict__ gz,
                                                 const float* __restrict__ gh,
                                                 float* __restrict__ state,
                                                 float* __restrict__ stateT) {
    const int lane = threadIdx.x & 63;
    const int i = blockIdx.x * 64 + lane;
    const int b = blockIdx.y * 4 + (threadIdx.x >> 6);
    const float az = gz[(size_t)b * UNITS + i];
    const float ah = gh[(size_t)b * UNITS + i];
    const float z = 1.f / (1.f + expf(-az));
    const float hh = tanhf(ah);
    const float st = (1.f - z) * hh;
    state[(size_t)b * UNITS + i] = st;
    stateT[(size_t)i * BATCH + b] = st;
}

// ---------------- K7: logits = stateT @ fc_W + fc_b ---------------------------------
__global__ __launch_bounds__(256, 2) void k_fc(const float* __restrict__ stateT,
                                               const float* __restrict__ fc_W,
                                               const float* __restrict__ fc_b,
                                               float* __restrict__ logits) {
    __shared__ float sState[1024 * 16];   // 64 KB; reused as 16 KB reduce buffer
    const int tid  = threadIdx.x;
    const int lane = tid & 63;
    const int wid  = tid >> 6;            // 0..3 -> K quarter
    const int g0   = blockIdx.y * 16;     // batch group
    const int col0 = blockIdx.x * 256 + lane * 4;

    // stage stateT[:, g0:g0+16] -> sState[row][16]
#pragma unroll
    for (int it = 0; it < 16; ++it) {
        const int idx = tid + it * 256;   // 0..4095
        const int r = idx >> 2, cch = idx & 3;
        const float4 v = *(const float4*)(stateT + (size_t)r * BATCH + g0 + cch * 4);
        *(float4*)&sState[r * 16 + cch * 4] = v;
    }

    const int krow0 = wid * 256;
    const float* wbase = fc_W + col0;

    // weight ring depth 4 (issued before the barrier to overlap staging)
    float4 wr[4];
#pragma unroll
    for (int j = 0; j < 4; ++j)
        wr[j] = *(const float4*)(wbase + (size_t)(krow0 + j) * VOCAB);

    __syncthreads();

    float4 acc[16];
#pragma unroll
    for (int b = 0; b < 16; ++b) acc[b] = (float4){0.f, 0.f, 0.f, 0.f};

    // state ring depth 2 (16 floats per slot)
    float4 srng[2][4];
#pragma unroll
    for (int c = 0; c < 4; ++c)
        srng[0][c] = *(const float4*)&sState[krow0 * 16 + c * 4];

#define FC_SUBSTEP(J, PREFETCH_W, PREFETCH_S)                                  \
    {                                                                          \
        const int r = krow0 + k + (J);                                         \
        if (PREFETCH_S) {                                                      \
            _Pragma("unroll")                                                  \
            for (int c = 0; c < 4; ++c)                                        \
                srng[((J) + 1) & 1][c] = *(const float4*)&sState[(r + 1) * 16 + c * 4]; \
        }                                                                      \
        const float4 wv = wr[(J)];                                             \
        if (PREFETCH_W)                                                        \
            wr[(J)] = *(const float4*)(wbase + (size_t)(r + 4) * VOCAB);       \
        _Pragma("unroll")                                                      \
        for (int c = 0; c < 4; ++c) {                                          \
            const float4 sv = srng[(J) & 1][c];                                \
            acc[c * 4 + 0].x = fmaf(wv.x, sv.x, acc[c * 4 + 0].x);             \
            acc[c * 4 + 0].y = fmaf(wv.y, sv.x, acc[c * 4 + 0].y);             \
            acc[c * 4 + 0].z = fmaf(wv.z, sv.x, acc[c * 4 + 0].z);             \
            acc[c * 4 + 0].w = fmaf(wv.w, sv.x, acc[c * 4 + 0].w);             \
            acc[c * 4 + 1].x = fmaf(wv.x, sv.y, acc[c * 4 + 1].x);             \
            acc[c * 4 + 1].y = fmaf(wv.y, sv.y, acc[c * 4 + 1].y);             \
            acc[c * 4 + 1].z = fmaf(wv.z, sv.y, acc[c * 4 + 1].z);             \
            acc[c * 4 + 1].w = fmaf(wv.w, sv.y, acc[c * 4 + 1].w);             \
            acc[c * 4 + 2].x = fmaf(wv.x, sv.z, acc[c * 4 + 2].x);             \
            acc[c * 4 + 2].y = fmaf(wv.y, sv.z, acc[c * 4 + 2].y);             \
            acc[c * 4 + 2].z = fmaf(wv.z, sv.z, acc[c * 4 + 2].z);             \
            acc[c * 4 + 2].w = fmaf(wv.w, sv.z, acc[c * 4 + 2].w);             \
            acc[c * 4 + 3].x = fmaf(wv.x, sv.w, acc[c * 4 + 3].x);             \
            acc[c * 4 + 3].y = fmaf(wv.y, sv.w, acc[c * 4 + 3].y);             \
            acc[c * 4 + 3].z = fmaf(wv.z, sv.w, acc[c * 4 + 3].z);             \
            acc[c * 4 + 3].w = fmaf(wv.w, sv.w, acc[c * 4 + 3].w);             \
        }                                                                      \
    }

    // main loop: rows krow0 .. krow0+251 (prefetch always in-bounds)
    for (int k = 0; k < 252; k += 4) {
        FC_SUBSTEP(0, true, true)
        FC_SUBSTEP(1, true, true)
        FC_SUBSTEP(2, true, true)
        FC_SUBSTEP(3, true, true)
    }
    // epilogue: rows krow0+252 .. krow0+255
    {
        const int k = 252;
        FC_SUBSTEP(0, false, true)
        FC_SUBSTEP(1, false, true)
        FC_SUBSTEP(2, false, true)
        FC_SUBSTEP(3, false, false)
    }
#undef FC_SUBSTEP

    // cross-wave reduce in LDS (reuse sState[0..4095] = 16 KB)
    __syncthreads();
    float* rbuf = sState;
#pragma unroll 1
    for (int ph = 0; ph < 4; ++ph) {
        if (wid == ph) {
#pragma unroll
            for (int b = 0; b < 16; ++b) {
                float4* p = (float4*)&rbuf[b * 256 + lane * 4];
                if (ph == 0) {
                    *p = acc[b];
                } else {
                    float4 t = *p;
                    t.x += acc[b].x; t.y += acc[b].y;
                    t.z += acc[b].z; t.w += acc[b].w;
                    *p = t;
                }
            }
        }
        __syncthreads();
    }

    // write out: thread t -> batch (t>>4), cols (t&15)*16 .. +15
    const int bb = tid >> 4;
    const int ch = tid & 15;
    const int cbase = blockIdx.x * 256 + ch * 16;
    float* lp = logits + (size_t)(g0 + bb) * VOCAB + cbase;
#pragma unroll
    for (int q = 0; q < 4; ++q) {
        float4 t = *(float4*)&rbuf[bb * 256 + ch * 16 + q * 4];
        const float4 fb = *(const float4*)(fc_b + cbase + q * 4);
        t.x += fb.x; t.y += fb.y; t.z += fb.z; t.w += fb.w;
        *(float4*)(lp + q * 4) = t;
    }
}

extern "C" void kernel_launch(void* const* d_in, const int* in_sizes, int n_in,
                              void* d_out, int out_size, void* d_ws, size_t ws_size,
                              hipStream_t stream) {
    const int*   x      = (const int*)  d_in[0];
    const float* hidden = (const float*)d_in[1];
    const float* enc    = (const float*)d_in[2];
    const float* emb    = (const float*)d_in[3];
    const float* W1     = (const float*)d_in[4];
    const float* b1     = (const float*)d_in[5];
    const float* W2     = (const float*)d_in[6];
    const float* b2     = (const float*)d_in[7];
    const float* V      = (const float*)d_in[8];
    // d_in[9] = bV: softmax-invariant. d_in[11] = gru_rk: multiplies h0==0. Both unused.
    const float* gru_k  = (const float*)d_in[10];
    const float* gru_b  = (const float*)d_in[12];
    const float* fc_W   = (const float*)d_in[13];
    const float* fc_b   = (const float*)d_in[14];

    float* out       = (float*)d_out;
    float* logits    = out;                          // 64*32000
    float* state_out = out + (size_t)BATCH * VOCAB;  // 64*1024
    float* attw      = state_out + (size_t)BATCH * UNITS;  // 64*128

    float* c      = (float*)d_ws;        // 65536 f
    float* score  = c + 65536;           // 8192 f
    float* gin    = score + 8192;        // 81920 f
    float* stateT = gin + 81920;         // 65536 f
    float* gz     = stateT + 65536;      // 65536 f
    float* gh     = gz + 65536;          // 65536 f
    unsigned short* w1t = (unsigned short*)(gh + 65536);   // 1024*1024 bf16 = 2 MB
    // total ws ~3.5 MB

    hipMemsetAsync(c, 0, (size_t)BATCH * UNITS * sizeof(float), stream);
    hipMemsetAsync(score, 0, (size_t)BATCH * TLEN * sizeof(float), stream);
    hipMemsetAsync(gz, 0, (size_t)2 * BATCH * UNITS * sizeof(float), stream);

    k_w1t    <<<dim3(16, 16),    256, 0, stream>>>(W1, w1t);
    k_c      <<<dim3(16, 16, 4), 256, 0, stream>>>(hidden, W2, b1, b2, c);
    k_score  <<<dim3(128, 8),    256, 0, stream>>>(enc, w1t, c, V, score);
    k_softmax<<<64, 64, 0, stream>>>(score, attw);
    k_context<<<dim3(4, 64),     256, 0, stream>>>(enc, attw, gin);
    k_embed  <<<64, 256, 0, stream>>>(x, emb, gin);
    k_gru_acc<<<dim3(16, 16, 5), 256, 0, stream>>>(gin, gru_k, gru_b, gz, gh);
    k_gru_fin<<<dim3(16, 16),    256, 0, stream>>>(gz, gh, state_out, stateT);
    k_fc     <<<dim3(125, 4),    256, 0, stream>>>(stateT, fc_W, fc_b, logits);
}

// Round 5
// 400.808 us; speedup vs baseline: 1.8187x; 1.0201x over previous
//
#include <hip/hip_runtime.h>
#include <math.h>

#define UNITS 1024
#define EMBD  256
#define BATCH 64
#define TLEN  128
#define VOCAB 32000
#define GIN_D (UNITS + EMBD)   // 1280

typedef short short8 __attribute__((ext_vector_type(8)));
typedef float f32x4  __attribute__((ext_vector_type(4)));

__device__ __forceinline__ unsigned short f2bf(float f) {
    unsigned int u = __float_as_uint(f);
    u += 0x7fffu + ((u >> 16) & 1u);   // RNE
    return (unsigned short)(u >> 16);
}

// ---------------- K0: W1T bf16 pre-transpose: w1t[j][k] = bf16(W1[k][j]) ------------
__global__ __launch_bounds__(256) void k_w1t(const float* __restrict__ W1,
                                             unsigned short* __restrict__ w1t) {
    __shared__ float t[64][65];
    const int tid = threadIdx.x;
    const int bx = blockIdx.x * 64;   // k base
    const int by = blockIdx.y * 64;   // j base
#pragma unroll
    for (int p = 0; p < 16; ++p) {
        const int idx = tid + p * 256;
        const int r = idx >> 6, cc = idx & 63;      // r: k-offset, cc: j-offset
        t[r][cc] = W1[(size_t)(bx + r) * UNITS + by + cc];
    }
    __syncthreads();
#pragma unroll
    for (int p = 0; p < 16; ++p) {
        const int idx = tid + p * 256;
        const int jr = idx >> 6, kc = idx & 63;     // jr: j-offset, kc: k-offset
        w1t[(size_t)(by + jr) * UNITS + bx + kc] = f2bf(t[kc][jr]);
    }
}

// ---------------- K1: c[b,j] += hidden @ W2  (b-tile 16, LDS-staged hidden) ---------
// grid (16, 4, 4): 64 j x 16 b x 256 k per block. W2 re-read 4x (was 16x).
__global__ __launch_bounds__(256) void k_c(const float* __restrict__ hidden,
                                           const float* __restrict__ W2,
                                           const float* __restrict__ b1,
                                           const float* __restrict__ b2,
                                           float* __restrict__ c) {
    __shared__ float sH[16][256];     // 16 KB
    const int tid = threadIdx.x;
    const int j = blockIdx.x * 64 + (tid & 63);
    const int g = tid >> 6;           // 0..3 -> 4 b's each
    const int b0 = blockIdx.y * 16;
    const int k0 = blockIdx.z * 256;
#pragma unroll
    for (int p = 0; p < 4; ++p) {
        const int fidx = tid + p * 256;            // float4 index 0..1023
        const int row = fidx >> 6, c4 = fidx & 63;
        *(float4*)&sH[row][c4 * 4] =
            *(const float4*)(hidden + (size_t)(b0 + row) * UNITS + k0 + c4 * 4);
    }
    __syncthreads();
    const float* wcol = W2 + (size_t)k0 * UNITS + j;
    float acc[4] = {0.f, 0.f, 0.f, 0.f};
    const int bb0 = g * 4;
#pragma unroll 8
    for (int k = 0; k < 256; ++k) {
        const float w = wcol[(size_t)k * UNITS];
        acc[0] = fmaf(w, sH[bb0 + 0][k], acc[0]);
        acc[1] = fmaf(w, sH[bb0 + 1][k], acc[1]);
        acc[2] = fmaf(w, sH[bb0 + 2][k], acc[2]);
        acc[3] = fmaf(w, sH[bb0 + 3][k], acc[3]);
    }
    if (blockIdx.z == 0) {
        const float bias = b1[j] + b2[j];
#pragma unroll
        for (int bb = 0; bb < 4; ++bb) acc[bb] += bias;
    }
#pragma unroll
    for (int bb = 0; bb < 4; ++bb)
        atomicAdd(&c[(size_t)(b0 + bb0 + bb) * UNITS + j], acc[bb]);
}

// ---------------- K2: score via bf16 MFMA, M=64 tile, bf16 W1T input ----------------
__global__ __launch_bounds__(256, 4) void k_score(const float* __restrict__ enc,
                                                  const unsigned short* __restrict__ w1t,
                                                  const float* __restrict__ c,
                                                  const float* __restrict__ V,
                                                  float* __restrict__ score) {
    __shared__ unsigned short As[64 * 72];
    __shared__ unsigned short Bs[128 * 72];
    const int half = blockIdx.x & 1;     // M-half of the 128 t-rows
    const int b    = blockIdx.x >> 1;    // 0..63
    const int jt   = blockIdx.y;         // 0..7
    const int tid  = threadIdx.x;
    const int lane = tid & 63;
    const int wc   = tid >> 6;           // wave -> N quarter (32 cols)
    const int quad = lane >> 4;
    const int l16  = lane & 15;

    const float* encb = enc + (size_t)b * TLEN * UNITS + (size_t)half * 64 * UNITS;
    const unsigned short* w1b = w1t + (size_t)jt * 128 * UNITS;

    f32x4 acc[4][2];
#pragma unroll
    for (int i = 0; i < 4; ++i)
#pragma unroll
        for (int j = 0; j < 2; ++j)
            acc[i][j] = (f32x4){0.f, 0.f, 0.f, 0.f};

    const int ar = tid >> 4;   // 0..15 (A row group)
    const int ac = tid & 15;   // 0..15 (A col chunk: 4 floats)

    for (int kc = 0; kc < UNITS; kc += 64) {
        float4 av[4];
#pragma unroll
        for (int rr = 0; rr < 4; ++rr)
            av[rr] = *(const float4*)(encb + (size_t)(ar + rr * 16) * UNITS + kc + ac * 4);
        short8 bv[4];
#pragma unroll
        for (int p = 0; p < 4; ++p) {
            const int cidx = tid + p * 256;          // 0..1023
            const int row = cidx >> 3, ch = cidx & 7;
            bv[p] = *(const short8*)(w1b + (size_t)row * UNITS + kc + ch * 8);
        }
        __syncthreads();
#pragma unroll
        for (int rr = 0; rr < 4; ++rr) {
            ushort4 h;
            h.x = f2bf(av[rr].x); h.y = f2bf(av[rr].y);
            h.z = f2bf(av[rr].z); h.w = f2bf(av[rr].w);
            *(ushort4*)&As[(ar + rr * 16) * 72 + ac * 4] = h;
        }
#pragma unroll
        for (int p = 0; p < 4; ++p) {
            const int cidx = tid + p * 256;
            const int row = cidx >> 3, ch = cidx & 7;
            *(short8*)&Bs[row * 72 + ch * 8] = bv[p];
        }
        __syncthreads();
#pragma unroll
        for (int kk = 0; kk < 2; ++kk) {
            const int kb = kk * 32 + quad * 8;
            short8 af[4], bfr[2];
#pragma unroll
            for (int mt = 0; mt < 4; ++mt)
                af[mt] = *(const short8*)&As[(mt * 16 + l16) * 72 + kb];
#pragma unroll
            for (int nt = 0; nt < 2; ++nt)
                bfr[nt] = *(const short8*)&Bs[(wc * 32 + nt * 16 + l16) * 72 + kb];
#pragma unroll
            for (int mt = 0; mt < 4; ++mt)
#pragma unroll
                for (int nt = 0; nt < 2; ++nt)
                    acc[mt][nt] = __builtin_amdgcn_mfma_f32_16x16x32_bf16(
                        af[mt], bfr[nt], acc[mt][nt], 0, 0, 0);
        }
    }

    float cv[2], vv[2];
#pragma unroll
    for (int nt = 0; nt < 2; ++nt) {
        const int col = jt * 128 + wc * 32 + nt * 16 + l16;
        cv[nt] = c[(size_t)b * UNITS + col];
        vv[nt] = V[col];
    }
    float rs[16];
#pragma unroll
    for (int mt = 0; mt < 4; ++mt)
#pragma unroll
        for (int reg = 0; reg < 4; ++reg) {
            float s = 0.f;
#pragma unroll
            for (int nt = 0; nt < 2; ++nt)
                s += tanhf(acc[mt][nt][reg] + cv[nt]) * vv[nt];
            rs[mt * 4 + reg] = s;
        }
#pragma unroll
    for (int off = 1; off < 16; off <<= 1)
#pragma unroll
        for (int i = 0; i < 16; ++i)
            rs[i] += __shfl_xor(rs[i], off);
    if (l16 == 0) {
#pragma unroll
        for (int mt = 0; mt < 4; ++mt)
#pragma unroll
            for (int reg = 0; reg < 4; ++reg)
                atomicAdd(&score[b * TLEN + half * 64 + mt * 16 + quad * 4 + reg],
                          rs[mt * 4 + reg]);
    }
}

// ---------------- K3: softmax over t ------------------------------------------------
__global__ void k_softmax(const float* __restrict__ score, float* __restrict__ attw) {
    const int b = blockIdx.x;
    const int lane = threadIdx.x;
    float s0 = score[b * TLEN + lane];
    float s1 = score[b * TLEN + 64 + lane];
    float m = fmaxf(s0, s1);
#pragma unroll
    for (int off = 1; off < 64; off <<= 1) m = fmaxf(m, __shfl_xor(m, off));
    const float e0 = expf(s0 - m);
    const float e1 = expf(s1 - m);
    float s = e0 + e1;
#pragma unroll
    for (int off = 1; off < 64; off <<= 1) s += __shfl_xor(s, off);
    const float inv = 1.f / s;
    attw[b * TLEN + lane] = e0 * inv;
    attw[b * TLEN + 64 + lane] = e1 * inv;
}

// ---------------- K4: context -> gin[:, :1024] --------------------------------------
__global__ __launch_bounds__(256) void k_context(const float* __restrict__ enc,
                                                 const float* __restrict__ attw,
                                                 float* __restrict__ gin) {
    const int b = blockIdx.y;
    const int k = blockIdx.x * 256 + threadIdx.x;
    __shared__ float w[TLEN];
    if (threadIdx.x < TLEN) w[threadIdx.x] = attw[b * TLEN + threadIdx.x];
    __syncthreads();
    const float* e = enc + (size_t)b * TLEN * UNITS + k;
    float acc = 0.f;
#pragma unroll 8
    for (int t = 0; t < TLEN; ++t)
        acc = fmaf(w[t], e[(size_t)t * UNITS], acc);
    gin[(size_t)b * GIN_D + k] = acc;
}

// ---------------- K5: embedding gather -> gin[:, 1024:1280] -------------------------
__global__ void k_embed(const int* __restrict__ x, const float* __restrict__ emb,
                        float* __restrict__ gin) {
    const int b = blockIdx.x;
    const int e = threadIdx.x;
    const int row = x[b];
    gin[(size_t)b * GIN_D + UNITS + e] = emb[(size_t)row * EMBD + e];
}

// ---------------- K6a: GRU gate accumulation (b-tile 16, LDS-staged gin) ------------
// grid (16, 4, 5): 64 i x 16 b x 256 k per block. gru_k re-read 4x (was 16x).
__global__ __launch_bounds__(256) void k_gru_acc(const float* __restrict__ gin,
                                                 const float* __restrict__ gru_k,
                                                 const float* __restrict__ gru_b,
                                                 float* __restrict__ gz,
                                                 float* __restrict__ gh) {
    __shared__ float sG[16][256];     // 16 KB
    const int tid = threadIdx.x;
    const int i = blockIdx.x * 64 + (tid & 63);
    const int g = tid >> 6;           // 0..3 -> 4 b's each
    const int b0 = blockIdx.y * 16;
    const int k0 = blockIdx.z * 256;
#pragma unroll
    for (int p = 0; p < 4; ++p) {
        const int fidx = tid + p * 256;
        const int row = fidx >> 6, c4 = fidx & 63;
        *(float4*)&sG[row][c4 * 4] =
            *(const float4*)(gin + (size_t)(b0 + row) * GIN_D + k0 + c4 * 4);
    }
    __syncthreads();
    const float* wz = gru_k + (size_t)k0 * 3072 + i;
    const float* wh = wz + 2048;
    float az[4] = {0.f, 0.f, 0.f, 0.f};
    float ah[4] = {0.f, 0.f, 0.f, 0.f};
    const int bb0 = g * 4;
#pragma unroll 4
    for (int k = 0; k < 256; ++k) {
        const float vz = wz[(size_t)k * 3072];
        const float vh = wh[(size_t)k * 3072];
        const float g0 = sG[bb0 + 0][k];
        const float g1 = sG[bb0 + 1][k];
        const float g2 = sG[bb0 + 2][k];
        const float g3 = sG[bb0 + 3][k];
        az[0] = fmaf(vz, g0, az[0]); ah[0] = fmaf(vh, g0, ah[0]);
        az[1] = fmaf(vz, g1, az[1]); ah[1] = fmaf(vh, g1, ah[1]);
        az[2] = fmaf(vz, g2, az[2]); ah[2] = fmaf(vh, g2, ah[2]);
        az[3] = fmaf(vz, g3, az[3]); ah[3] = fmaf(vh, g3, ah[3]);
    }
    if (blockIdx.z == 0) {
        const float bz = gru_b[i], bh = gru_b[2048 + i];
#pragma unroll
        for (int bb = 0; bb < 4; ++bb) { az[bb] += bz; ah[bb] += bh; }
    }
#pragma unroll
    for (int bb = 0; bb < 4; ++bb) {
        atomicAdd(&gz[(size_t)(b0 + bb0 + bb) * UNITS + i], az[bb]);
        atomicAdd(&gh[(size_t)(b0 + bb0 + bb) * UNITS + i], ah[bb]);
    }
}

// ---------------- K6b: GRU finalize -------------------------------------------------
__global__ __launch_bounds__(256) void k_gru_fin(const float* __restrict__ gz,
                                                 const float* __restrict__ gh,
                                                 float* __restrict__ state,
                                                 float* __restrict__ stateT) {
    const int lane = threadIdx.x & 63;
    const int i = blockIdx.x * 64 + lane;
    const int b = blockIdx.y * 4 + (threadIdx.x >> 6);
    const float az = gz[(size_t)b * UNITS + i];
    const float ah = gh[(size_t)b * UNITS + i];
    const float z = 1.f / (1.f + expf(-az));
    const float hh = tanhf(ah);
    const float st = (1.f - z) * hh;
    state[(size_t)b * UNITS + i] = st;
    stateT[(size_t)i * BATCH + b] = st;
}

// ---------------- K7: logits = stateT @ fc_W + fc_b ---------------------------------
// XCD-swizzled 1D grid (512): xcd = flat&7, y = (flat>>3)&3, x = (flat>>5)*8 + xcd.
// All 4 y-blocks of one column-tile x land on the same XCD (round-robin dispatch)
// and run concurrently -> 3 of 4 fc_W streams hit that XCD's L2 instead of HBM.
__global__ __launch_bounds__(256, 2) void k_fc(const float* __restrict__ stateT,
                                               const float* __restrict__ fc_W,
                                               const float* __restrict__ fc_b,
                                               float* __restrict__ logits) {
    __shared__ float sState[1024 * 16];   // 64 KB; reused as 16 KB reduce buffer
    const int flat = blockIdx.x;
    const int xcd  = flat & 7;
    const int rest = flat >> 3;
    const int by   = rest & 3;            // batch group 0..3
    const int bx   = (rest >> 2) * 8 + xcd;   // column tile 0..127
    if (bx >= 125) return;

    const int tid  = threadIdx.x;
    const int lane = tid & 63;
    const int wid  = tid >> 6;            // 0..3 -> K quarter
    const int g0   = by * 16;             // batch group base
    const int col0 = bx * 256 + lane * 4;

    // stage stateT[:, g0:g0+16] -> sState[row][16]
#pragma unroll
    for (int it = 0; it < 16; ++it) {
        const int idx = tid + it * 256;   // 0..4095
        const int r = idx >> 2, cch = idx & 3;
        const float4 v = *(const float4*)(stateT + (size_t)r * BATCH + g0 + cch * 4);
        *(float4*)&sState[r * 16 + cch * 4] = v;
    }

    const int krow0 = wid * 256;
    const float* wbase = fc_W + col0;

    // weight ring depth 4 (issued before the barrier to overlap staging)
    float4 wr[4];
#pragma unroll
    for (int j = 0; j < 4; ++j)
        wr[j] = *(const float4*)(wbase + (size_t)(krow0 + j) * VOCAB);

    __syncthreads();

    float4 acc[16];
#pragma unroll
    for (int b = 0; b < 16; ++b) acc[b] = (float4){0.f, 0.f, 0.f, 0.f};

    // state ring depth 2 (16 floats per slot)
    float4 srng[2][4];
#pragma unroll
    for (int c = 0; c < 4; ++c)
        srng[0][c] = *(const float4*)&sState[krow0 * 16 + c * 4];

#define FC_SUBSTEP(J, PREFETCH_W, PREFETCH_S)                                  \
    {                                                                          \
        const int r = krow0 + k + (J);                                         \
        if (PREFETCH_S) {                                                      \
            _Pragma("unroll")                                                  \
            for (int c = 0; c < 4; ++c)                                        \
                srng[((J) + 1) & 1][c] = *(const float4*)&sState[(r + 1) * 16 + c * 4]; \
        }                                                                      \
        const float4 wv = wr[(J)];                                             \
        if (PREFETCH_W)                                                        \
            wr[(J)] = *(const float4*)(wbase + (size_t)(r + 4) * VOCAB);       \
        _Pragma("unroll")                                                      \
        for (int c = 0; c < 4; ++c) {                                          \
            const float4 sv = srng[(J) & 1][c];                                \
            acc[c * 4 + 0].x = fmaf(wv.x, sv.x, acc[c * 4 + 0].x);             \
            acc[c * 4 + 0].y = fmaf(wv.y, sv.x, acc[c * 4 + 0].y);             \
            acc[c * 4 + 0].z = fmaf(wv.z, sv.x, acc[c * 4 + 0].z);             \
            acc[c * 4 + 0].w = fmaf(wv.w, sv.x, acc[c * 4 + 0].w);             \
            acc[c * 4 + 1].x = fmaf(wv.x, sv.y, acc[c * 4 + 1].x);             \
            acc[c * 4 + 1].y = fmaf(wv.y, sv.y, acc[c * 4 + 1].y);             \
            acc[c * 4 + 1].z = fmaf(wv.z, sv.y, acc[c * 4 + 1].z);             \
            acc[c * 4 + 1].w = fmaf(wv.w, sv.y, acc[c * 4 + 1].w);             \
            acc[c * 4 + 2].x = fmaf(wv.x, sv.z, acc[c * 4 + 2].x);             \
            acc[c * 4 + 2].y = fmaf(wv.y, sv.z, acc[c * 4 + 2].y);             \
            acc[c * 4 + 2].z = fmaf(wv.z, sv.z, acc[c * 4 + 2].z);             \
            acc[c * 4 + 2].w = fmaf(wv.w, sv.z, acc[c * 4 + 2].w);             \
            acc[c * 4 + 3].x = fmaf(wv.x, sv.w, acc[c * 4 + 3].x);             \
            acc[c * 4 + 3].y = fmaf(wv.y, sv.w, acc[c * 4 + 3].y);             \
            acc[c * 4 + 3].z = fmaf(wv.z, sv.w, acc[c * 4 + 3].z);             \
            acc[c * 4 + 3].w = fmaf(wv.w, sv.w, acc[c * 4 + 3].w);             \
        }                                                                      \
    }

    // main loop: rows krow0 .. krow0+251 (prefetch always in-bounds)
    for (int k = 0; k < 252; k += 4) {
        FC_SUBSTEP(0, true, true)
        FC_SUBSTEP(1, true, true)
        FC_SUBSTEP(2, true, true)
        FC_SUBSTEP(3, true, true)
    }
    // epilogue: rows krow0+252 .. krow0+255
    {
        const int k = 252;
        FC_SUBSTEP(0, false, true)
        FC_SUBSTEP(1, false, true)
        FC_SUBSTEP(2, false, true)
        FC_SUBSTEP(3, false, false)
    }
#undef FC_SUBSTEP

    // cross-wave reduce in LDS (reuse sState[0..4095] = 16 KB)
    __syncthreads();
    float* rbuf = sState;
#pragma unroll 1
    for (int ph = 0; ph < 4; ++ph) {
        if (wid == ph) {
#pragma unroll
            for (int b = 0; b < 16; ++b) {
                float4* p = (float4*)&rbuf[b * 256 + lane * 4];
                if (ph == 0) {
                    *p = acc[b];
                } else {
                    float4 t = *p;
                    t.x += acc[b].x; t.y += acc[b].y;
                    t.z += acc[b].z; t.w += acc[b].w;
                    *p = t;
                }
            }
        }
        __syncthreads();
    }

    // write out: thread t -> batch (t>>4), cols (t&15)*16 .. +15
    const int bb = tid >> 4;
    const int ch = tid & 15;
    const int cbase = bx * 256 + ch * 16;
    float* lp = logits + (size_t)(g0 + bb) * VOCAB + cbase;
#pragma unroll
    for (int q = 0; q < 4; ++q) {
        float4 t = *(float4*)&rbuf[bb * 256 + ch * 16 + q * 4];
        const float4 fb = *(const float4*)(fc_b + cbase + q * 4);
        t.x += fb.x; t.y += fb.y; t.z += fb.z; t.w += fb.w;
        *(float4*)(lp + q * 4) = t;
    }
}

extern "C" void kernel_launch(void* const* d_in, const int* in_sizes, int n_in,
                              void* d_out, int out_size, void* d_ws, size_t ws_size,
                              hipStream_t stream) {
    const int*   x      = (const int*)  d_in[0];
    const float* hidden = (const float*)d_in[1];
    const float* enc    = (const float*)d_in[2];
    const float* emb    = (const float*)d_in[3];
    const float* W1     = (const float*)d_in[4];
    const float* b1     = (const float*)d_in[5];
    const float* W2     = (const float*)d_in[6];
    const float* b2     = (const float*)d_in[7];
    const float* V      = (const float*)d_in[8];
    // d_in[9] = bV: softmax-invariant. d_in[11] = gru_rk: multiplies h0==0. Both unused.
    const float* gru_k  = (const float*)d_in[10];
    const float* gru_b  = (const float*)d_in[12];
    const float* fc_W   = (const float*)d_in[13];
    const float* fc_b   = (const float*)d_in[14];

    float* out       = (float*)d_out;
    float* logits    = out;                          // 64*32000
    float* state_out = out + (size_t)BATCH * VOCAB;  // 64*1024
    float* attw      = state_out + (size_t)BATCH * UNITS;  // 64*128

    float* c      = (float*)d_ws;        // 65536 f
    float* score  = c + 65536;           // 8192 f
    float* gin    = score + 8192;        // 81920 f
    float* stateT = gin + 81920;         // 65536 f
    float* gz     = stateT + 65536;      // 65536 f
    float* gh     = gz + 65536;          // 65536 f
    unsigned short* w1t = (unsigned short*)(gh + 65536);   // 1024*1024 bf16 = 2 MB
    // total ws ~3.5 MB

    hipMemsetAsync(c, 0, (size_t)BATCH * UNITS * sizeof(float), stream);
    hipMemsetAsync(score, 0, (size_t)BATCH * TLEN * sizeof(float), stream);
    hipMemsetAsync(gz, 0, (size_t)2 * BATCH * UNITS * sizeof(float), stream);

    k_w1t    <<<dim3(16, 16),    256, 0, stream>>>(W1, w1t);
    k_c      <<<dim3(16, 4, 4),  256, 0, stream>>>(hidden, W2, b1, b2, c);
    k_score  <<<dim3(128, 8),    256, 0, stream>>>(enc, w1t, c, V, score);
    k_softmax<<<64, 64, 0, stream>>>(score, attw);
    k_context<<<dim3(4, 64),     256, 0, stream>>>(enc, attw, gin);
    k_embed  <<<64, 256, 0, stream>>>(x, emb, gin);
    k_gru_acc<<<dim3(16, 4, 5),  256, 0, stream>>>(gin, gru_k, gru_b, gz, gh);
    k_gru_fin<<<dim3(16, 16),    256, 0, stream>>>(gz, gh, state_out, stateT);
    k_fc     <<<dim3(512),       256, 0, stream>>>(stateT, fc_W, fc_b, logits);
}